// Round 11
// baseline (154.209 us; speedup 1.0000x reference)
//
#include <hip/hip_runtime.h>

#define N_NODES 50000
#define N_EDGES 600000
#define D 128
#define SCAN_B 256
#define NB ((N_NODES + SCAN_B - 1) / SCAN_B)   // 196 blocks
#define REP 4
#define FXSHIFT 44
#define GEMM_BLOCKS ((N_NODES + 63) / 64)       // 782
#define FILL_BLOCKS ((N_EDGES + 255) / 256)     // 2344
#define ZERO_BLOCKS 392

typedef __attribute__((ext_vector_type(8))) short short8;
typedef __attribute__((ext_vector_type(4))) float f32x4;
typedef unsigned long long u64;

__device__ __forceinline__ ushort f2bf(float f) {
    unsigned u = __float_as_uint(f);
    unsigned r = (u + 0x7FFFu + ((u >> 16) & 1u)) >> 16;   // RNE
    return (ushort)r;
}
__device__ __forceinline__ float bf2f(ushort h) {
    return __uint_as_float(((unsigned)h) << 16);
}

// ---------------------------------------------------------------------------
// W fragment computation (hi/lo bf16 split), MFMA B-operand lane order.
// ---------------------------------------------------------------------------
__device__ __forceinline__ void wfrag_body(int t, const float* __restrict__ W,
                                           ushort* __restrict__ wfh,
                                           ushort* __restrict__ wfl) {
    int lane = t & 63;
    int ks   = (t >> 6) & 3;
    int ct   = t >> 8;
    int n  = ct * 16 + (lane & 15);
    int k0 = ks * 32 + (lane >> 4) * 8;
    ushort hv[8], lv[8];
#pragma unroll
    for (int j = 0; j < 8; ++j) {
        float v = W[(k0 + j) * D + n];
        ushort hh = f2bf(v);
        hv[j] = hh;
        lv[j] = f2bf(v - bf2f(hh));
    }
    size_t base = (((size_t)ct * 4 + ks) * 64 + lane) * 8;
#pragma unroll
    for (int j = 0; j < 8; ++j) { wfh[base + j] = hv[j]; wfl[base + j] = lv[j]; }
}

// ---------------------------------------------------------------------------
// Prep (fat): blocks [0,ZERO_BLOCKS) zero degp+flags; the last 8 do wfrag.
// ---------------------------------------------------------------------------
__global__ void prep_kernel(ulonglong2* __restrict__ zp, int n2,
                            const float* __restrict__ W,
                            ushort* __restrict__ wfh, ushort* __restrict__ wfl) {
    if (blockIdx.x < ZERO_BLOCKS) {
        int i = blockIdx.x * 256 + threadIdx.x;
        if (i < n2) zp[i] = make_ulonglong2(0ull, 0ull);
    } else {
        wfrag_body((blockIdx.x - ZERO_BLOCKS) * 256 + threadIdx.x, W, wfh, wfl);
    }
}

// ---------------------------------------------------------------------------
// Per-edge: one packed u64 atomic into one of REP replicas.
// ---------------------------------------------------------------------------
__global__ void deg_cnt_kernel(const int* __restrict__ dst,
                               const float* __restrict__ ew,
                               u64* __restrict__ degp) {
    int e = blockIdx.x * 256 + threadIdx.x;
    if (e < N_EDGES) {
        int d = dst[e];
        int r = blockIdx.x & (REP - 1);
        u64 fx = (u64)llrintf(ew[e] * 16777216.0f);
        atomicAdd(&degp[(size_t)r * N_NODES + d], (1ull << FXSHIFT) | fx);
    }
}

// ---------------------------------------------------------------------------
// Single-pass fused scan (decoupled lookback, acquire/release flag ops):
// replica-sum -> dinv; exclusive scan -> off + per-replica cursors.
// ---------------------------------------------------------------------------
__global__ void scan_fused_kernel(const u64* __restrict__ degp,
                                  float* __restrict__ dinv,
                                  int* __restrict__ off,
                                  int* __restrict__ cursor,
                                  u64* __restrict__ flags) {
    __shared__ int s[SCAN_B];
    __shared__ int sbase_sh;
    int t = threadIdx.x;
    int i = blockIdx.x * SCAN_B + t;
    int v = 0;
    u64 pr[REP];
    if (i < N_NODES) {
        u64 fxsum = 0;
        int c = 0;
#pragma unroll
        for (int r = 0; r < REP; ++r) {
            pr[r] = degp[(size_t)r * N_NODES + i];
            fxsum += pr[r] & ((1ull << FXSHIFT) - 1);
            c += (int)(pr[r] >> FXSHIFT);
        }
        float deg = 1.0f + (float)fxsum * (1.0f / 16777216.0f);
        dinv[i] = rsqrtf(deg);
        v = c;
    }
    s[t] = v;
    __syncthreads();
    for (int o = 1; o < SCAN_B; o <<= 1) {
        int x = (t >= o) ? s[t - o] : 0;
        __syncthreads();
        s[t] += x;
        __syncthreads();
    }
    int localExcl = s[t] - v;
    int blockSum  = s[SCAN_B - 1];

    if (t == 0) {
        u64 agg = (u64)blockSum;
        int sb = 0;
        if (blockIdx.x == 0) {
            __hip_atomic_store(&flags[0], (2ull << 62) | agg,
                               __ATOMIC_RELEASE, __HIP_MEMORY_SCOPE_AGENT);
        } else {
            __hip_atomic_store(&flags[blockIdx.x], (1ull << 62) | agg,
                               __ATOMIC_RELEASE, __HIP_MEMORY_SCOPE_AGENT);
            u64 run = 0;
            for (int j = blockIdx.x - 1; j >= 0; --j) {
                u64 f;
                do {
                    f = __hip_atomic_load(&flags[j], __ATOMIC_ACQUIRE,
                                          __HIP_MEMORY_SCOPE_AGENT);
                } while ((f >> 62) == 0ull);
                run += f & ((1ull << 62) - 1);
                if ((f >> 62) == 2ull) break;
            }
            sb = (int)run;
            __hip_atomic_store(&flags[blockIdx.x], (2ull << 62) | (agg + (u64)sb),
                               __ATOMIC_RELEASE, __HIP_MEMORY_SCOPE_AGENT);
        }
        sbase_sh = sb;
    }
    __syncthreads();

    if (i < N_NODES) {
        int o = localExcl + sbase_sh;
        off[i] = o;
        int run = o;
#pragma unroll
        for (int r = 0; r < REP; ++r) {
            cursor[(size_t)r * N_NODES + i] = run;
            run += (int)(pr[r] >> FXSHIFT);
        }
    }
    if (i == 0) off[N_NODES] = N_EDGES;
}

// ---------------------------------------------------------------------------
// Fat compute kernel, INTERLEAVED: (b&3)==0 -> gemm tile b>>2 (782 total);
// else fill chunk b-1-(b>>2) (2344 total). Gemm (MFMA) and fill (atomics)
// blocks co-resident on every CU from t=0 -> mutual latency hiding.
// ---------------------------------------------------------------------------
__global__ __launch_bounds__(256) void fused_fg_kernel(
        const float* __restrict__ x,
        const ushort* __restrict__ wfh, const ushort* __restrict__ wfl,
        ushort* __restrict__ hbf,
        const int* __restrict__ src, const int* __restrict__ dst,
        const float* __restrict__ ew, const float* __restrict__ dinv,
        int* __restrict__ cursor, u64* __restrict__ edge_s) {
    __shared__ __attribute__((aligned(16))) ushort xh[64 * 128];

    int t = threadIdx.x;
    int b = blockIdx.x;
    if ((b & 3) == 0) {
        // ---------------- gemm: h = x_hi * W (hi/lo W split) ----------------
        int gb = b >> 2;                      // 0..781
        int r0 = gb * 64;
#pragma unroll
        for (int p = 0; p < 8; ++p) {
            int row  = p * 8 + (t >> 5);
            int g    = t & 31;
            int grow = r0 + row;
            float4 v = make_float4(0.f, 0.f, 0.f, 0.f);
            if (grow < N_NODES) v = ((const float4*)(x + (size_t)grow * D))[g];
            ushort4 hi;
            hi.x = f2bf(v.x); hi.y = f2bf(v.y); hi.z = f2bf(v.z); hi.w = f2bf(v.w);
            int bo = (row * 256 + g * 8) ^ ((row & 7) << 4);
            *(ushort4*)((char*)xh + bo) = hi;
        }
        __syncthreads();

        int w  = t >> 6;
        int l  = t & 63;
        int m  = l & 15;
        int gq = l >> 4;

        f32x4 acc[8];
#pragma unroll
        for (int ct = 0; ct < 8; ++ct) acc[ct] = (f32x4){0.f, 0.f, 0.f, 0.f};

#pragma unroll
        for (int ks = 0; ks < 4; ++ks) {
            int row = w * 16 + m;
            int bo  = (row * 256 + gq * 16 + ks * 64) ^ ((row & 7) << 4);
            short8 ah = *(const short8*)((const char*)xh + bo);
#pragma unroll
            for (int ct = 0; ct < 8; ++ct) {
                size_t fb = (((size_t)ct * 4 + ks) * 64 + l) * 8;
                short8 bh = *(const short8*)(wfh + fb);
                short8 bl = *(const short8*)(wfl + fb);
                acc[ct] = __builtin_amdgcn_mfma_f32_16x16x32_bf16(ah, bh, acc[ct], 0, 0, 0);
                acc[ct] = __builtin_amdgcn_mfma_f32_16x16x32_bf16(ah, bl, acc[ct], 0, 0, 0);
            }
        }

        int orow0 = r0 + w * 16 + gq * 4;
#pragma unroll
        for (int ct = 0; ct < 8; ++ct) {
#pragma unroll
            for (int r = 0; r < 4; ++r) {
                int row = orow0 + r;
                if (row < N_NODES) hbf[(size_t)row * D + ct * 16 + m] = f2bf(acc[ct][r]);
            }
        }
    } else {
        // ---------------- fill: dst-sorted packed edges ----------------
        int fb = b - 1 - (b >> 2);            // 0..2343
        int e = fb * 256 + t;
        if (e >= N_EDGES) return;
        int s = src[e];
        int d = dst[e];
        int r = fb & (REP - 1);               // matches deg_cnt's e>>8 & 3
        int pos = atomicAdd(&cursor[(size_t)r * N_NODES + d], 1);
        float w = ew[e] * dinv[s] * dinv[d];
        edge_s[pos] = ((u64)__float_as_uint(w) << 32) | (unsigned)s;
    }
}

// ---------------------------------------------------------------------------
// Gather: one wave per node, 4-way split (16 lanes x interleaved edge quarters)
// ---------------------------------------------------------------------------
__global__ __launch_bounds__(256) void gather_kernel(
        const int* __restrict__ off, const u64* __restrict__ edge_s,
        const float* __restrict__ dinv,
        const ushort* __restrict__ hbf, const float* __restrict__ b,
        float* __restrict__ out) {
    int node = blockIdx.x * 4 + (threadIdx.x >> 6);
    if (node >= N_NODES) return;
    int lane = threadIdx.x & 63;
    int q  = lane >> 4;
    int fl = lane & 15;

    int begin = off[node];
    int end   = off[node + 1];
    float dd  = dinv[node];
    float sw  = dd * dd;

    float acc[8] = {0.f, 0.f, 0.f, 0.f, 0.f, 0.f, 0.f, 0.f};

    short8 sv = ((const short8*)(hbf + (size_t)node * D))[fl];
    if (q == 0) {
#pragma unroll
        for (int j = 0; j < 8; ++j) acc[j] = bf2f((ushort)sv[j]) * sw;
    }

    for (int j0 = begin; j0 < end; j0 += 64) {
        int nc = end - j0;
        if (nc > 64) nc = 64;
        u64 p = 0;
        if (lane < nc) p = edge_s[j0 + lane];
        int iters = (nc + 3) >> 2;
#pragma unroll 2
        for (int t = 0; t < iters; ++t) {
            int ei = t * 4 + q;
            u64 pe = __shfl((long long)p, ei);
            bool valid = ei < nc;
            int   ss = valid ? (int)(pe & 0xFFFFFFFFu) : 0;
            float ww = valid ? __uint_as_float((unsigned)(pe >> 32)) : 0.0f;
            short8 v = ((const short8*)(hbf + (size_t)ss * D))[fl];
#pragma unroll
            for (int j = 0; j < 8; ++j)
                acc[j] = fmaf(bf2f((ushort)v[j]), ww, acc[j]);
        }
    }

#pragma unroll
    for (int j = 0; j < 8; ++j) {
        acc[j] += __shfl_xor(acc[j], 16);
        acc[j] += __shfl_xor(acc[j], 32);
    }

    if (q == 0) {
        float4 b1 = ((const float4*)b)[fl * 2];
        float4 b2 = ((const float4*)b)[fl * 2 + 1];
        float4 o1 = make_float4(fmaxf(acc[0] + b1.x, 0.f), fmaxf(acc[1] + b1.y, 0.f),
                                fmaxf(acc[2] + b1.z, 0.f), fmaxf(acc[3] + b1.w, 0.f));
        float4 o2 = make_float4(fmaxf(acc[4] + b2.x, 0.f), fmaxf(acc[5] + b2.y, 0.f),
                                fmaxf(acc[6] + b2.z, 0.f), fmaxf(acc[7] + b2.w, 0.f));
        ((float4*)(out + (size_t)node * D))[fl * 2]     = o1;
        ((float4*)(out + (size_t)node * D))[fl * 2 + 1] = o2;
    }
}

// ---------------------------------------------------------------------------
// Fallback path (small ws): R0-style atomic scatter, f32 throughout.
// ---------------------------------------------------------------------------
__global__ void fb_init_kernel(float* __restrict__ deg) {
    int i = blockIdx.x * 256 + threadIdx.x;
    if (i < N_NODES) deg[i] = 1.0f;
}
__global__ void fb_deg_kernel(const int* __restrict__ dst, const float* __restrict__ ew,
                              float* __restrict__ deg) {
    int e = blockIdx.x * 256 + threadIdx.x;
    if (e < N_EDGES) atomicAdd(&deg[dst[e]], ew[e]);
}
__global__ void fb_dinv_kernel(const float* __restrict__ deg, float* __restrict__ dinv) {
    int i = blockIdx.x * 256 + threadIdx.x;
    if (i < N_NODES) {
        float d = deg[i];
        dinv[i] = (d > 0.0f) ? rsqrtf(d) : 0.0f;
    }
}
__global__ void fb_gemm_kernel(const float* __restrict__ x, const float* __restrict__ W,
                               float* __restrict__ h) {
    __shared__ float xs[2][D];
    int lr  = threadIdx.x >> 7;
    int col = threadIdx.x & 127;
    int row = blockIdx.x * 2 + lr;
    if (row < N_NODES) xs[lr][col] = x[(size_t)row * D + col];
    __syncthreads();
    if (row >= N_NODES) return;
    float acc = 0.0f;
#pragma unroll 8
    for (int k = 0; k < D; ++k) acc = fmaf(xs[lr][k], W[k * D + col], acc);
    h[(size_t)row * D + col] = acc;
}
__global__ void fb_scatter_kernel(const int* __restrict__ src, const int* __restrict__ dst,
                                  const float* __restrict__ ew, const float* __restrict__ dinv,
                                  const float* __restrict__ h, float* __restrict__ acc) {
    int e = blockIdx.x * 4 + (threadIdx.x >> 6);
    if (e >= N_EDGES) return;
    int lane = threadIdx.x & 63;
    int s = src[e];
    int d = dst[e];
    float w = ew[e] * dinv[s] * dinv[d];
    float2 v = ((const float2*)(h + (size_t)s * D))[lane];
    float* ap = acc + (size_t)d * D + lane * 2;
    atomicAdd(ap,     v.x * w);
    atomicAdd(ap + 1, v.y * w);
}
__global__ void fb_finalize_kernel(const float* __restrict__ h, const float* __restrict__ dinv,
                                   const float* __restrict__ b, float* __restrict__ out) {
    int i = blockIdx.x * 256 + threadIdx.x;
    if (i >= N_NODES * D) return;
    int node = i >> 7;
    int col  = i & 127;
    float di = dinv[node];
    float v = out[i] + h[i] * di * di + b[col];
    out[i] = fmaxf(v, 0.0f);
}

extern "C" void kernel_launch(void* const* d_in, const int* in_sizes, int n_in,
                              void* d_out, int out_size, void* d_ws, size_t ws_size,
                              hipStream_t stream) {
    const float* x  = (const float*)d_in[0];
    const int*   ei = (const int*)d_in[1];   // [2, E]: src row then dst row
    const float* ew = (const float*)d_in[2];
    const float* W  = (const float*)d_in[3];
    const float* b  = (const float*)d_in[4];
    float*       out = (float*)d_out;

    const int* src = ei;
    const int* dst = ei + N_EDGES;

    // ---- main-path workspace layout (all offsets 8B-aligned) ----
    ushort* hbf    = (ushort*)d_ws;                           // N*D bf16  (12.8 MB)
    u64*    degp   = (u64*)(hbf + (size_t)N_NODES * D);       // REP*N u64 (1.6 MB)
    u64*    flags  = degp + (size_t)REP * N_NODES;            // 256 u64
    float*  dinv   = (float*)(flags + 256);                   // N
    int*    off    = (int*)(dinv + N_NODES);                  // N+2 (padded)
    int*    cursor = off + (N_NODES + 2);                     // REP*N
    u64*    edge_s = (u64*)(cursor + (size_t)REP * N_NODES);  // E u64 (4.8 MB)
    ushort* wfh    = (ushort*)(edge_s + N_EDGES);             // 16384
    ushort* wfl    = wfh + 16384;                             // 16384
    size_t need = ((size_t)(wfl + 16384) - (size_t)d_ws);

    if (ws_size >= need) {
        int n2 = (int)(((size_t)REP * N_NODES * 8 + 256 * 8) / 16);
        prep_kernel<<<ZERO_BLOCKS + 8, 256, 0, stream>>>((ulonglong2*)degp, n2,
                                                         W, wfh, wfl);

        deg_cnt_kernel<<<FILL_BLOCKS, 256, 0, stream>>>(dst, ew, degp);

        scan_fused_kernel<<<NB, SCAN_B, 0, stream>>>(degp, dinv, off, cursor, flags);

        fused_fg_kernel<<<GEMM_BLOCKS + FILL_BLOCKS, 256, 0, stream>>>(
            x, wfh, wfl, hbf, src, dst, ew, dinv, cursor, edge_s);

        gather_kernel<<<(N_NODES + 3) / 4, 256, 0, stream>>>(off, edge_s, dinv,
                                                             hbf, b, out);
    } else {
        // ---- fallback: atomic scatter, f32 ----
        float* h    = (float*)d_ws;                 // N*D
        float* deg  = h + (size_t)N_NODES * D;      // N
        float* dv   = deg + N_NODES;                // N
        hipMemsetAsync(d_out, 0, (size_t)out_size * sizeof(float), stream);
        fb_init_kernel<<<(N_NODES + 255) / 256, 256, 0, stream>>>(deg);
        fb_deg_kernel<<<(N_EDGES + 255) / 256, 256, 0, stream>>>(dst, ew, deg);
        fb_dinv_kernel<<<(N_NODES + 255) / 256, 256, 0, stream>>>(deg, dv);
        fb_gemm_kernel<<<(N_NODES + 1) / 2, 256, 0, stream>>>(x, W, h);
        fb_scatter_kernel<<<(N_EDGES + 3) / 4, 256, 0, stream>>>(src, dst, ew, dv, h, out);
        fb_finalize_kernel<<<(N_NODES * D + 255) / 256, 256, 0, stream>>>(h, dv, b, out);
    }
}

// Round 12
// 145.114 us; speedup vs baseline: 1.0627x; 1.0627x over previous
//
#include <hip/hip_runtime.h>

#define N_NODES 50000
#define N_EDGES 600000
#define D 128
#define SCAN_B 256
#define NB ((N_NODES + SCAN_B - 1) / SCAN_B)   // 196 blocks
#define REP 4
#define FXSHIFT 44
#define GEMM_BLOCKS ((N_NODES + 31) / 32)       // 1563 (32-row tiles)
#define FILL_BLOCKS ((N_EDGES + 255) / 256)     // 2344
#define ZERO_BLOCKS 392

typedef __attribute__((ext_vector_type(8))) short short8;
typedef __attribute__((ext_vector_type(4))) float f32x4;
typedef unsigned long long u64;

__device__ __forceinline__ ushort f2bf(float f) {
    unsigned u = __float_as_uint(f);
    unsigned r = (u + 0x7FFFu + ((u >> 16) & 1u)) >> 16;   // RNE
    return (ushort)r;
}
__device__ __forceinline__ float bf2f(ushort h) {
    return __uint_as_float(((unsigned)h) << 16);
}

// ---------------------------------------------------------------------------
// W fragment computation (hi/lo bf16 split), MFMA B-operand lane order.
// ---------------------------------------------------------------------------
__device__ __forceinline__ void wfrag_body(int t, const float* __restrict__ W,
                                           ushort* __restrict__ wfh,
                                           ushort* __restrict__ wfl) {
    int lane = t & 63;
    int ks   = (t >> 6) & 3;
    int ct   = t >> 8;
    int n  = ct * 16 + (lane & 15);
    int k0 = ks * 32 + (lane >> 4) * 8;
    ushort hv[8], lv[8];
#pragma unroll
    for (int j = 0; j < 8; ++j) {
        float v = W[(k0 + j) * D + n];
        ushort hh = f2bf(v);
        hv[j] = hh;
        lv[j] = f2bf(v - bf2f(hh));
    }
    size_t base = (((size_t)ct * 4 + ks) * 64 + lane) * 8;
#pragma unroll
    for (int j = 0; j < 8; ++j) { wfh[base + j] = hv[j]; wfl[base + j] = lv[j]; }
}

// ---------------------------------------------------------------------------
// Prep (fat): blocks [0,ZERO_BLOCKS) zero degp+flags; the last 8 do wfrag.
// ---------------------------------------------------------------------------
__global__ void prep_kernel(ulonglong2* __restrict__ zp, int n2,
                            const float* __restrict__ W,
                            ushort* __restrict__ wfh, ushort* __restrict__ wfl) {
    if (blockIdx.x < ZERO_BLOCKS) {
        int i = blockIdx.x * 256 + threadIdx.x;
        if (i < n2) zp[i] = make_ulonglong2(0ull, 0ull);
    } else {
        wfrag_body((blockIdx.x - ZERO_BLOCKS) * 256 + threadIdx.x, W, wfh, wfl);
    }
}

// ---------------------------------------------------------------------------
// Per-edge: one packed u64 atomic into one of REP replicas.
// ---------------------------------------------------------------------------
__global__ void deg_cnt_kernel(const int* __restrict__ dst,
                               const float* __restrict__ ew,
                               u64* __restrict__ degp) {
    int e = blockIdx.x * 256 + threadIdx.x;
    if (e < N_EDGES) {
        int d = dst[e];
        int r = blockIdx.x & (REP - 1);
        u64 fx = (u64)llrintf(ew[e] * 16777216.0f);
        atomicAdd(&degp[(size_t)r * N_NODES + d], (1ull << FXSHIFT) | fx);
    }
}

// ---------------------------------------------------------------------------
// Single-pass fused scan (decoupled lookback, acquire/release flag ops):
// replica-sum -> dinv; exclusive scan -> off + per-replica cursors.
// ---------------------------------------------------------------------------
__global__ void scan_fused_kernel(const u64* __restrict__ degp,
                                  float* __restrict__ dinv,
                                  int* __restrict__ off,
                                  int* __restrict__ cursor,
                                  u64* __restrict__ flags) {
    __shared__ int s[SCAN_B];
    __shared__ int sbase_sh;
    int t = threadIdx.x;
    int i = blockIdx.x * SCAN_B + t;
    int v = 0;
    u64 pr[REP];
    if (i < N_NODES) {
        u64 fxsum = 0;
        int c = 0;
#pragma unroll
        for (int r = 0; r < REP; ++r) {
            pr[r] = degp[(size_t)r * N_NODES + i];
            fxsum += pr[r] & ((1ull << FXSHIFT) - 1);
            c += (int)(pr[r] >> FXSHIFT);
        }
        float deg = 1.0f + (float)fxsum * (1.0f / 16777216.0f);
        dinv[i] = rsqrtf(deg);
        v = c;
    }
    s[t] = v;
    __syncthreads();
    for (int o = 1; o < SCAN_B; o <<= 1) {
        int x = (t >= o) ? s[t - o] : 0;
        __syncthreads();
        s[t] += x;
        __syncthreads();
    }
    int localExcl = s[t] - v;
    int blockSum  = s[SCAN_B - 1];

    if (t == 0) {
        u64 agg = (u64)blockSum;
        int sb = 0;
        if (blockIdx.x == 0) {
            __hip_atomic_store(&flags[0], (2ull << 62) | agg,
                               __ATOMIC_RELEASE, __HIP_MEMORY_SCOPE_AGENT);
        } else {
            __hip_atomic_store(&flags[blockIdx.x], (1ull << 62) | agg,
                               __ATOMIC_RELEASE, __HIP_MEMORY_SCOPE_AGENT);
            u64 run = 0;
            for (int j = blockIdx.x - 1; j >= 0; --j) {
                u64 f;
                do {
                    f = __hip_atomic_load(&flags[j], __ATOMIC_ACQUIRE,
                                          __HIP_MEMORY_SCOPE_AGENT);
                } while ((f >> 62) == 0ull);
                run += f & ((1ull << 62) - 1);
                if ((f >> 62) == 2ull) break;
            }
            sb = (int)run;
            __hip_atomic_store(&flags[blockIdx.x], (2ull << 62) | (agg + (u64)sb),
                               __ATOMIC_RELEASE, __HIP_MEMORY_SCOPE_AGENT);
        }
        sbase_sh = sb;
    }
    __syncthreads();

    if (i < N_NODES) {
        int o = localExcl + sbase_sh;
        off[i] = o;
        int run = o;
#pragma unroll
        for (int r = 0; r < REP; ++r) {
            cursor[(size_t)r * N_NODES + i] = run;
            run += (int)(pr[r] >> FXSHIFT);
        }
    }
    if (i == 0) off[N_NODES] = N_EDGES;
}

// ---------------------------------------------------------------------------
// Fat compute kernel, SEQUENTIAL layout (R10-proven; interleave regressed):
// blocks [0,GEMM_BLOCKS) = gemm 32-row tiles; rest = fill.
// 32-row tiles double the gemm block count -> ~6 blocks/CU residency in the
// gemm burst (was 3) -> latency hidden. Wave w: rows (w&1)*16..+16, col half
// (w>>1)*64 (4 ct tiles). 8 KB LDS, 16 acc regs.
// ---------------------------------------------------------------------------
__global__ __launch_bounds__(256) void fused_fg_kernel(
        const float* __restrict__ x,
        const ushort* __restrict__ wfh, const ushort* __restrict__ wfl,
        ushort* __restrict__ hbf,
        const int* __restrict__ src, const int* __restrict__ dst,
        const float* __restrict__ ew, const float* __restrict__ dinv,
        int* __restrict__ cursor, u64* __restrict__ edge_s) {
    __shared__ __attribute__((aligned(16))) ushort xh[32 * 128];

    int t = threadIdx.x;
    int b = blockIdx.x;
    if (b < GEMM_BLOCKS) {
        // ---------------- gemm: h = x_hi * W (hi/lo W split) ----------------
        int r0 = b * 32;
#pragma unroll
        for (int p = 0; p < 4; ++p) {
            int row  = p * 8 + (t >> 5);
            int g    = t & 31;
            int grow = r0 + row;
            float4 v = make_float4(0.f, 0.f, 0.f, 0.f);
            if (grow < N_NODES) v = ((const float4*)(x + (size_t)grow * D))[g];
            ushort4 hi;
            hi.x = f2bf(v.x); hi.y = f2bf(v.y); hi.z = f2bf(v.z); hi.w = f2bf(v.w);
            int bo = (row * 256 + g * 8) ^ ((row & 7) << 4);
            *(ushort4*)((char*)xh + bo) = hi;
        }
        __syncthreads();

        int w  = t >> 6;
        int l  = t & 63;
        int m  = l & 15;
        int gq = l >> 4;
        int mrow = (w & 1) * 16 + m;          // row within 32-row tile
        int ct0  = (w >> 1) * 4;              // column half: ct0..ct0+3

        f32x4 acc[4];
#pragma unroll
        for (int c = 0; c < 4; ++c) acc[c] = (f32x4){0.f, 0.f, 0.f, 0.f};

#pragma unroll
        for (int ks = 0; ks < 4; ++ks) {
            int bo = (mrow * 256 + gq * 16 + ks * 64) ^ ((mrow & 7) << 4);
            short8 ah = *(const short8*)((const char*)xh + bo);
#pragma unroll
            for (int c = 0; c < 4; ++c) {
                int ct = ct0 + c;
                size_t fb = (((size_t)ct * 4 + ks) * 64 + l) * 8;
                short8 bh = *(const short8*)(wfh + fb);
                short8 bl = *(const short8*)(wfl + fb);
                acc[c] = __builtin_amdgcn_mfma_f32_16x16x32_bf16(ah, bh, acc[c], 0, 0, 0);
                acc[c] = __builtin_amdgcn_mfma_f32_16x16x32_bf16(ah, bl, acc[c], 0, 0, 0);
            }
        }

        int orow0 = r0 + (w & 1) * 16 + gq * 4;
#pragma unroll
        for (int c = 0; c < 4; ++c) {
            int col = (ct0 + c) * 16 + m;
#pragma unroll
            for (int r = 0; r < 4; ++r) {
                int row = orow0 + r;
                if (row < N_NODES) hbf[(size_t)row * D + col] = f2bf(acc[c][r]);
            }
        }
    } else {
        // ---------------- fill: dst-sorted packed edges ----------------
        int fb = b - GEMM_BLOCKS;
        int e = fb * 256 + t;
        if (e >= N_EDGES) return;
        int s = src[e];
        int d = dst[e];
        int r = fb & (REP - 1);               // matches deg_cnt's replica map
        int pos = atomicAdd(&cursor[(size_t)r * N_NODES + d], 1);
        float w = ew[e] * dinv[s] * dinv[d];
        edge_s[pos] = ((u64)__float_as_uint(w) << 32) | (unsigned)s;
    }
}

// ---------------------------------------------------------------------------
// Gather: one wave per node, 4-way split (16 lanes x interleaved edge quarters)
// ---------------------------------------------------------------------------
__global__ __launch_bounds__(256) void gather_kernel(
        const int* __restrict__ off, const u64* __restrict__ edge_s,
        const float* __restrict__ dinv,
        const ushort* __restrict__ hbf, const float* __restrict__ b,
        float* __restrict__ out) {
    int node = blockIdx.x * 4 + (threadIdx.x >> 6);
    if (node >= N_NODES) return;
    int lane = threadIdx.x & 63;
    int q  = lane >> 4;
    int fl = lane & 15;

    int begin = off[node];
    int end   = off[node + 1];
    float dd  = dinv[node];
    float sw  = dd * dd;

    float acc[8] = {0.f, 0.f, 0.f, 0.f, 0.f, 0.f, 0.f, 0.f};

    short8 sv = ((const short8*)(hbf + (size_t)node * D))[fl];
    if (q == 0) {
#pragma unroll
        for (int j = 0; j < 8; ++j) acc[j] = bf2f((ushort)sv[j]) * sw;
    }

    for (int j0 = begin; j0 < end; j0 += 64) {
        int nc = end - j0;
        if (nc > 64) nc = 64;
        u64 p = 0;
        if (lane < nc) p = edge_s[j0 + lane];
        int iters = (nc + 3) >> 2;
#pragma unroll 2
        for (int t = 0; t < iters; ++t) {
            int ei = t * 4 + q;
            u64 pe = __shfl((long long)p, ei);
            bool valid = ei < nc;
            int   ss = valid ? (int)(pe & 0xFFFFFFFFu) : 0;
            float ww = valid ? __uint_as_float((unsigned)(pe >> 32)) : 0.0f;
            short8 v = ((const short8*)(hbf + (size_t)ss * D))[fl];
#pragma unroll
            for (int j = 0; j < 8; ++j)
                acc[j] = fmaf(bf2f((ushort)v[j]), ww, acc[j]);
        }
    }

#pragma unroll
    for (int j = 0; j < 8; ++j) {
        acc[j] += __shfl_xor(acc[j], 16);
        acc[j] += __shfl_xor(acc[j], 32);
    }

    if (q == 0) {
        float4 b1 = ((const float4*)b)[fl * 2];
        float4 b2 = ((const float4*)b)[fl * 2 + 1];
        float4 o1 = make_float4(fmaxf(acc[0] + b1.x, 0.f), fmaxf(acc[1] + b1.y, 0.f),
                                fmaxf(acc[2] + b1.z, 0.f), fmaxf(acc[3] + b1.w, 0.f));
        float4 o2 = make_float4(fmaxf(acc[4] + b2.x, 0.f), fmaxf(acc[5] + b2.y, 0.f),
                                fmaxf(acc[6] + b2.z, 0.f), fmaxf(acc[7] + b2.w, 0.f));
        ((float4*)(out + (size_t)node * D))[fl * 2]     = o1;
        ((float4*)(out + (size_t)node * D))[fl * 2 + 1] = o2;
    }
}

// ---------------------------------------------------------------------------
// Fallback path (small ws): R0-style atomic scatter, f32 throughout.
// ---------------------------------------------------------------------------
__global__ void fb_init_kernel(float* __restrict__ deg) {
    int i = blockIdx.x * 256 + threadIdx.x;
    if (i < N_NODES) deg[i] = 1.0f;
}
__global__ void fb_deg_kernel(const int* __restrict__ dst, const float* __restrict__ ew,
                              float* __restrict__ deg) {
    int e = blockIdx.x * 256 + threadIdx.x;
    if (e < N_EDGES) atomicAdd(&deg[dst[e]], ew[e]);
}
__global__ void fb_dinv_kernel(const float* __restrict__ deg, float* __restrict__ dinv) {
    int i = blockIdx.x * 256 + threadIdx.x;
    if (i < N_NODES) {
        float d = deg[i];
        dinv[i] = (d > 0.0f) ? rsqrtf(d) : 0.0f;
    }
}
__global__ void fb_gemm_kernel(const float* __restrict__ x, const float* __restrict__ W,
                               float* __restrict__ h) {
    __shared__ float xs[2][D];
    int lr  = threadIdx.x >> 7;
    int col = threadIdx.x & 127;
    int row = blockIdx.x * 2 + lr;
    if (row < N_NODES) xs[lr][col] = x[(size_t)row * D + col];
    __syncthreads();
    if (row >= N_NODES) return;
    float acc = 0.0f;
#pragma unroll 8
    for (int k = 0; k < D; ++k) acc = fmaf(xs[lr][k], W[k * D + col], acc);
    h[(size_t)row * D + col] = acc;
}
__global__ void fb_scatter_kernel(const int* __restrict__ src, const int* __restrict__ dst,
                                  const float* __restrict__ ew, const float* __restrict__ dinv,
                                  const float* __restrict__ h, float* __restrict__ acc) {
    int e = blockIdx.x * 4 + (threadIdx.x >> 6);
    if (e >= N_EDGES) return;
    int lane = threadIdx.x & 63;
    int s = src[e];
    int d = dst[e];
    float w = ew[e] * dinv[s] * dinv[d];
    float2 v = ((const float2*)(h + (size_t)s * D))[lane];
    float* ap = acc + (size_t)d * D + lane * 2;
    atomicAdd(ap,     v.x * w);
    atomicAdd(ap + 1, v.y * w);
}
__global__ void fb_finalize_kernel(const float* __restrict__ h, const float* __restrict__ dinv,
                                   const float* __restrict__ b, float* __restrict__ out) {
    int i = blockIdx.x * 256 + threadIdx.x;
    if (i >= N_NODES * D) return;
    int node = i >> 7;
    int col  = i & 127;
    float di = dinv[node];
    float v = out[i] + h[i] * di * di + b[col];
    out[i] = fmaxf(v, 0.0f);
}

extern "C" void kernel_launch(void* const* d_in, const int* in_sizes, int n_in,
                              void* d_out, int out_size, void* d_ws, size_t ws_size,
                              hipStream_t stream) {
    const float* x  = (const float*)d_in[0];
    const int*   ei = (const int*)d_in[1];   // [2, E]: src row then dst row
    const float* ew = (const float*)d_in[2];
    const float* W  = (const float*)d_in[3];
    const float* b  = (const float*)d_in[4];
    float*       out = (float*)d_out;

    const int* src = ei;
    const int* dst = ei + N_EDGES;

    // ---- main-path workspace layout (all offsets 8B-aligned) ----
    ushort* hbf    = (ushort*)d_ws;                           // N*D bf16  (12.8 MB)
    u64*    degp   = (u64*)(hbf + (size_t)N_NODES * D);       // REP*N u64 (1.6 MB)
    u64*    flags  = degp + (size_t)REP * N_NODES;            // 256 u64
    float*  dinv   = (float*)(flags + 256);                   // N
    int*    off    = (int*)(dinv + N_NODES);                  // N+2 (padded)
    int*    cursor = off + (N_NODES + 2);                     // REP*N
    u64*    edge_s = (u64*)(cursor + (size_t)REP * N_NODES);  // E u64 (4.8 MB)
    ushort* wfh    = (ushort*)(edge_s + N_EDGES);             // 16384
    ushort* wfl    = wfh + 16384;                             // 16384
    size_t need = ((size_t)(wfl + 16384) - (size_t)d_ws);

    if (ws_size >= need) {
        int n2 = (int)(((size_t)REP * N_NODES * 8 + 256 * 8) / 16);
        prep_kernel<<<ZERO_BLOCKS + 8, 256, 0, stream>>>((ulonglong2*)degp, n2,
                                                         W, wfh, wfl);

        deg_cnt_kernel<<<FILL_BLOCKS, 256, 0, stream>>>(dst, ew, degp);

        scan_fused_kernel<<<NB, SCAN_B, 0, stream>>>(degp, dinv, off, cursor, flags);

        fused_fg_kernel<<<GEMM_BLOCKS + FILL_BLOCKS, 256, 0, stream>>>(
            x, wfh, wfl, hbf, src, dst, ew, dinv, cursor, edge_s);

        gather_kernel<<<(N_NODES + 3) / 4, 256, 0, stream>>>(off, edge_s, dinv,
                                                             hbf, b, out);
    } else {
        // ---- fallback: atomic scatter, f32 ----
        float* h    = (float*)d_ws;                 // N*D
        float* deg  = h + (size_t)N_NODES * D;      // N
        float* dv   = deg + N_NODES;                // N
        hipMemsetAsync(d_out, 0, (size_t)out_size * sizeof(float), stream);
        fb_init_kernel<<<(N_NODES + 255) / 256, 256, 0, stream>>>(deg);
        fb_deg_kernel<<<(N_EDGES + 255) / 256, 256, 0, stream>>>(dst, ew, deg);
        fb_dinv_kernel<<<(N_NODES + 255) / 256, 256, 0, stream>>>(deg, dv);
        fb_gemm_kernel<<<(N_NODES + 1) / 2, 256, 0, stream>>>(x, W, h);
        fb_scatter_kernel<<<(N_EDGES + 3) / 4, 256, 0, stream>>>(src, dst, ew, dv, h, out);
        fb_finalize_kernel<<<(N_NODES * D + 255) / 256, 256, 0, stream>>>(h, dv, b, out);
    }
}

// Round 13
// 112.275 us; speedup vs baseline: 1.3735x; 1.2925x over previous
//
#include <hip/hip_runtime.h>

#define N_NODES 50000
#define N_EDGES 600000
#define D 128
#define SCAN_B 256
#define NB ((N_NODES + SCAN_B - 1) / SCAN_B)   // 196 blocks
#define REP 4
#define FXSHIFT 44
#define GEMM_BLOCKS ((N_NODES + 63) / 64)       // 782 (R10-proven 64-row tiles)
#define FILL_BLOCKS ((N_EDGES + 255) / 256)     // 2344
#define ZERO_BLOCKS 392

typedef __attribute__((ext_vector_type(8))) short short8;
typedef __attribute__((ext_vector_type(4))) float f32x4;
typedef unsigned long long u64;

__device__ __forceinline__ ushort f2bf(float f) {
    unsigned u = __float_as_uint(f);
    unsigned r = (u + 0x7FFFu + ((u >> 16) & 1u)) >> 16;   // RNE
    return (ushort)r;
}
__device__ __forceinline__ float bf2f(ushort h) {
    return __uint_as_float(((unsigned)h) << 16);
}

// ---------------------------------------------------------------------------
// W fragment computation (hi/lo bf16 split), MFMA B-operand lane order.
// ---------------------------------------------------------------------------
__device__ __forceinline__ void wfrag_body(int t, const float* __restrict__ W,
                                           ushort* __restrict__ wfh,
                                           ushort* __restrict__ wfl) {
    int lane = t & 63;
    int ks   = (t >> 6) & 3;
    int ct   = t >> 8;
    int n  = ct * 16 + (lane & 15);
    int k0 = ks * 32 + (lane >> 4) * 8;
    ushort hv[8], lv[8];
#pragma unroll
    for (int j = 0; j < 8; ++j) {
        float v = W[(k0 + j) * D + n];
        ushort hh = f2bf(v);
        hv[j] = hh;
        lv[j] = f2bf(v - bf2f(hh));
    }
    size_t base = (((size_t)ct * 4 + ks) * 64 + lane) * 8;
#pragma unroll
    for (int j = 0; j < 8; ++j) { wfh[base + j] = hv[j]; wfl[base + j] = lv[j]; }
}

// ---------------------------------------------------------------------------
// Prep (fat): blocks [0,ZERO_BLOCKS) zero degp+flags; the last 8 do wfrag.
// ---------------------------------------------------------------------------
__global__ void prep_kernel(ulonglong2* __restrict__ zp, int n2,
                            const float* __restrict__ W,
                            ushort* __restrict__ wfh, ushort* __restrict__ wfl) {
    if (blockIdx.x < ZERO_BLOCKS) {
        int i = blockIdx.x * 256 + threadIdx.x;
        if (i < n2) zp[i] = make_ulonglong2(0ull, 0ull);
    } else {
        wfrag_body((blockIdx.x - ZERO_BLOCKS) * 256 + threadIdx.x, W, wfh, wfl);
    }
}

// ---------------------------------------------------------------------------
// Per-edge: one packed u64 atomic. degp layout INTERLEAVED: [node*REP + r]
// (scan reads become 32B contiguous per node).
// ---------------------------------------------------------------------------
__global__ void deg_cnt_kernel(const int* __restrict__ dst,
                               const float* __restrict__ ew,
                               u64* __restrict__ degp) {
    int e = blockIdx.x * 256 + threadIdx.x;
    if (e < N_EDGES) {
        int d = dst[e];
        int r = blockIdx.x & (REP - 1);
        u64 fx = (u64)llrintf(ew[e] * 16777216.0f);
        atomicAdd(&degp[(size_t)d * REP + r], (1ull << FXSHIFT) | fx);
    }
}

// ---------------------------------------------------------------------------
// Single-pass fused scan with WAVE-PARALLEL AGGREGATE RAKE (no serial
// inclusive chain): every block publishes its aggregate; block k's wave 0
// spin-reads all k predecessor aggregates 64-at-a-time and reduces.
// All 196 blocks co-resident -> no deadlock; only lower-indexed waits.
// ---------------------------------------------------------------------------
__global__ void scan_fused_kernel(const u64* __restrict__ degp,
                                  float* __restrict__ dinv,
                                  int* __restrict__ off,
                                  int* __restrict__ cursor,
                                  u64* __restrict__ flags) {
    __shared__ int s[SCAN_B];
    __shared__ int sbase_sh;
    int t = threadIdx.x;
    int i = blockIdx.x * SCAN_B + t;
    int v = 0;
    u64 pr[REP];
    if (i < N_NODES) {
        u64 fxsum = 0;
        int c = 0;
        const u64* dp = degp + (size_t)i * REP;
#pragma unroll
        for (int r = 0; r < REP; ++r) {
            pr[r] = dp[r];
            fxsum += pr[r] & ((1ull << FXSHIFT) - 1);
            c += (int)(pr[r] >> FXSHIFT);
        }
        float deg = 1.0f + (float)fxsum * (1.0f / 16777216.0f);
        dinv[i] = rsqrtf(deg);
        v = c;
    }
    s[t] = v;
    __syncthreads();
    for (int o = 1; o < SCAN_B; o <<= 1) {
        int x = (t >= o) ? s[t - o] : 0;
        __syncthreads();
        s[t] += x;
        __syncthreads();
    }
    int localExcl = s[t] - v;
    int blockSum  = s[SCAN_B - 1];

    // publish aggregate (status bit 62), then wave 0 rakes predecessors
    if (t == 0) {
        __hip_atomic_store(&flags[blockIdx.x], (1ull << 62) | (u64)blockSum,
                           __ATOMIC_RELEASE, __HIP_MEMORY_SCOPE_AGENT);
    }
    if (t < 64) {
        u64 sum = 0;
        for (int j0 = 0; j0 < (int)blockIdx.x; j0 += 64) {
            int j = j0 + t;
            u64 f = 0;
            if (j < (int)blockIdx.x) {
                do {
                    f = __hip_atomic_load(&flags[j], __ATOMIC_ACQUIRE,
                                          __HIP_MEMORY_SCOPE_AGENT);
                } while (f == 0ull);
            }
            sum += f & ((1ull << 62) - 1);
        }
#pragma unroll
        for (int o = 32; o > 0; o >>= 1)
            sum += (u64)__shfl_xor((long long)sum, o);
        if (t == 0) sbase_sh = (int)sum;
    }
    __syncthreads();

    if (i < N_NODES) {
        int o = localExcl + sbase_sh;
        off[i] = o;
        int run = o;
        int* cp = cursor + (size_t)i * REP;        // interleaved, coalesced
#pragma unroll
        for (int r = 0; r < REP; ++r) {
            cp[r] = run;
            run += (int)(pr[r] >> FXSHIFT);
        }
    }
    if (i == 0) off[N_NODES] = N_EDGES;
}

// ---------------------------------------------------------------------------
// Fat compute kernel, SEQUENTIAL layout, R10-proven 64-row gemm tiles:
// blocks [0,GEMM_BLOCKS) = gemm; rest = fill (cursor interleaved [d*REP+r]).
// ---------------------------------------------------------------------------
__global__ __launch_bounds__(256) void fused_fg_kernel(
        const float* __restrict__ x,
        const ushort* __restrict__ wfh, const ushort* __restrict__ wfl,
        ushort* __restrict__ hbf,
        const int* __restrict__ src, const int* __restrict__ dst,
        const float* __restrict__ ew, const float* __restrict__ dinv,
        int* __restrict__ cursor, u64* __restrict__ edge_s) {
    __shared__ __attribute__((aligned(16))) ushort xh[64 * 128];

    int t = threadIdx.x;
    int b = blockIdx.x;
    if (b < GEMM_BLOCKS) {
        // ---------------- gemm: h = x_hi * W (hi/lo W split) ----------------
        int r0 = b * 64;
#pragma unroll
        for (int p = 0; p < 8; ++p) {
            int row  = p * 8 + (t >> 5);
            int g    = t & 31;
            int grow = r0 + row;
            float4 v = make_float4(0.f, 0.f, 0.f, 0.f);
            if (grow < N_NODES) v = ((const float4*)(x + (size_t)grow * D))[g];
            ushort4 hi;
            hi.x = f2bf(v.x); hi.y = f2bf(v.y); hi.z = f2bf(v.z); hi.w = f2bf(v.w);
            int bo = (row * 256 + g * 8) ^ ((row & 7) << 4);
            *(ushort4*)((char*)xh + bo) = hi;
        }
        __syncthreads();

        int w  = t >> 6;
        int l  = t & 63;
        int m  = l & 15;
        int gq = l >> 4;

        f32x4 acc[8];
#pragma unroll
        for (int ct = 0; ct < 8; ++ct) acc[ct] = (f32x4){0.f, 0.f, 0.f, 0.f};

#pragma unroll
        for (int ks = 0; ks < 4; ++ks) {
            int row = w * 16 + m;
            int bo  = (row * 256 + gq * 16 + ks * 64) ^ ((row & 7) << 4);
            short8 ah = *(const short8*)((const char*)xh + bo);
#pragma unroll
            for (int ct = 0; ct < 8; ++ct) {
                size_t fb = (((size_t)ct * 4 + ks) * 64 + l) * 8;
                short8 bh = *(const short8*)(wfh + fb);
                short8 bl = *(const short8*)(wfl + fb);
                acc[ct] = __builtin_amdgcn_mfma_f32_16x16x32_bf16(ah, bh, acc[ct], 0, 0, 0);
                acc[ct] = __builtin_amdgcn_mfma_f32_16x16x32_bf16(ah, bl, acc[ct], 0, 0, 0);
            }
        }

        int orow0 = r0 + w * 16 + gq * 4;
#pragma unroll
        for (int ct = 0; ct < 8; ++ct) {
#pragma unroll
            for (int r = 0; r < 4; ++r) {
                int row = orow0 + r;
                if (row < N_NODES) hbf[(size_t)row * D + ct * 16 + m] = f2bf(acc[ct][r]);
            }
        }
    } else {
        // ---------------- fill: dst-sorted packed edges ----------------
        int fb = b - GEMM_BLOCKS;
        int e = fb * 256 + t;
        if (e >= N_EDGES) return;
        int s = src[e];
        int d = dst[e];
        int r = fb & (REP - 1);               // matches deg_cnt's replica map
        int pos = atomicAdd(&cursor[(size_t)d * REP + r], 1);
        float w = ew[e] * dinv[s] * dinv[d];
        edge_s[pos] = ((u64)__float_as_uint(w) << 32) | (unsigned)s;
    }
}

// ---------------------------------------------------------------------------
// Gather: one wave per node, 4-way split (16 lanes x interleaved edge quarters)
// ---------------------------------------------------------------------------
__global__ __launch_bounds__(256) void gather_kernel(
        const int* __restrict__ off, const u64* __restrict__ edge_s,
        const float* __restrict__ dinv,
        const ushort* __restrict__ hbf, const float* __restrict__ b,
        float* __restrict__ out) {
    int node = blockIdx.x * 4 + (threadIdx.x >> 6);
    if (node >= N_NODES) return;
    int lane = threadIdx.x & 63;
    int q  = lane >> 4;
    int fl = lane & 15;

    int begin = off[node];
    int end   = off[node + 1];
    float dd  = dinv[node];
    float sw  = dd * dd;

    float acc[8] = {0.f, 0.f, 0.f, 0.f, 0.f, 0.f, 0.f, 0.f};

    short8 sv = ((const short8*)(hbf + (size_t)node * D))[fl];
    if (q == 0) {
#pragma unroll
        for (int j = 0; j < 8; ++j) acc[j] = bf2f((ushort)sv[j]) * sw;
    }

    for (int j0 = begin; j0 < end; j0 += 64) {
        int nc = end - j0;
        if (nc > 64) nc = 64;
        u64 p = 0;
        if (lane < nc) p = edge_s[j0 + lane];
        int iters = (nc + 3) >> 2;
#pragma unroll 2
        for (int t = 0; t < iters; ++t) {
            int ei = t * 4 + q;
            u64 pe = __shfl((long long)p, ei);
            bool valid = ei < nc;
            int   ss = valid ? (int)(pe & 0xFFFFFFFFu) : 0;
            float ww = valid ? __uint_as_float((unsigned)(pe >> 32)) : 0.0f;
            short8 v = ((const short8*)(hbf + (size_t)ss * D))[fl];
#pragma unroll
            for (int j = 0; j < 8; ++j)
                acc[j] = fmaf(bf2f((ushort)v[j]), ww, acc[j]);
        }
    }

#pragma unroll
    for (int j = 0; j < 8; ++j) {
        acc[j] += __shfl_xor(acc[j], 16);
        acc[j] += __shfl_xor(acc[j], 32);
    }

    if (q == 0) {
        float4 b1 = ((const float4*)b)[fl * 2];
        float4 b2 = ((const float4*)b)[fl * 2 + 1];
        float4 o1 = make_float4(fmaxf(acc[0] + b1.x, 0.f), fmaxf(acc[1] + b1.y, 0.f),
                                fmaxf(acc[2] + b1.z, 0.f), fmaxf(acc[3] + b1.w, 0.f));
        float4 o2 = make_float4(fmaxf(acc[4] + b2.x, 0.f), fmaxf(acc[5] + b2.y, 0.f),
                                fmaxf(acc[6] + b2.z, 0.f), fmaxf(acc[7] + b2.w, 0.f));
        ((float4*)(out + (size_t)node * D))[fl * 2]     = o1;
        ((float4*)(out + (size_t)node * D))[fl * 2 + 1] = o2;
    }
}

// ---------------------------------------------------------------------------
// Fallback path (small ws): R0-style atomic scatter, f32 throughout.
// ---------------------------------------------------------------------------
__global__ void fb_init_kernel(float* __restrict__ deg) {
    int i = blockIdx.x * 256 + threadIdx.x;
    if (i < N_NODES) deg[i] = 1.0f;
}
__global__ void fb_deg_kernel(const int* __restrict__ dst, const float* __restrict__ ew,
                              float* __restrict__ deg) {
    int e = blockIdx.x * 256 + threadIdx.x;
    if (e < N_EDGES) atomicAdd(&deg[dst[e]], ew[e]);
}
__global__ void fb_dinv_kernel(const float* __restrict__ deg, float* __restrict__ dinv) {
    int i = blockIdx.x * 256 + threadIdx.x;
    if (i < N_NODES) {
        float d = deg[i];
        dinv[i] = (d > 0.0f) ? rsqrtf(d) : 0.0f;
    }
}
__global__ void fb_gemm_kernel(const float* __restrict__ x, const float* __restrict__ W,
                               float* __restrict__ h) {
    __shared__ float xs[2][D];
    int lr  = threadIdx.x >> 7;
    int col = threadIdx.x & 127;
    int row = blockIdx.x * 2 + lr;
    if (row < N_NODES) xs[lr][col] = x[(size_t)row * D + col];
    __syncthreads();
    if (row >= N_NODES) return;
    float acc = 0.0f;
#pragma unroll 8
    for (int k = 0; k < D; ++k) acc = fmaf(xs[lr][k], W[k * D + col], acc);
    h[(size_t)row * D + col] = acc;
}
__global__ void fb_scatter_kernel(const int* __restrict__ src, const int* __restrict__ dst,
                                  const float* __restrict__ ew, const float* __restrict__ dinv,
                                  const float* __restrict__ h, float* __restrict__ acc) {
    int e = blockIdx.x * 4 + (threadIdx.x >> 6);
    if (e >= N_EDGES) return;
    int lane = threadIdx.x & 63;
    int s = src[e];
    int d = dst[e];
    float w = ew[e] * dinv[s] * dinv[d];
    float2 v = ((const float2*)(h + (size_t)s * D))[lane];
    float* ap = acc + (size_t)d * D + lane * 2;
    atomicAdd(ap,     v.x * w);
    atomicAdd(ap + 1, v.y * w);
}
__global__ void fb_finalize_kernel(const float* __restrict__ h, const float* __restrict__ dinv,
                                   const float* __restrict__ b, float* __restrict__ out) {
    int i = blockIdx.x * 256 + threadIdx.x;
    if (i >= N_NODES * D) return;
    int node = i >> 7;
    int col  = i & 127;
    float di = dinv[node];
    float v = out[i] + h[i] * di * di + b[col];
    out[i] = fmaxf(v, 0.0f);
}

extern "C" void kernel_launch(void* const* d_in, const int* in_sizes, int n_in,
                              void* d_out, int out_size, void* d_ws, size_t ws_size,
                              hipStream_t stream) {
    const float* x  = (const float*)d_in[0];
    const int*   ei = (const int*)d_in[1];   // [2, E]: src row then dst row
    const float* ew = (const float*)d_in[2];
    const float* W  = (const float*)d_in[3];
    const float* b  = (const float*)d_in[4];
    float*       out = (float*)d_out;

    const int* src = ei;
    const int* dst = ei + N_EDGES;

    // ---- main-path workspace layout (all offsets 8B-aligned) ----
    ushort* hbf    = (ushort*)d_ws;                           // N*D bf16  (12.8 MB)
    u64*    degp   = (u64*)(hbf + (size_t)N_NODES * D);       // N*REP u64 (1.6 MB), [i*REP+r]
    u64*    flags  = degp + (size_t)REP * N_NODES;            // 256 u64
    float*  dinv   = (float*)(flags + 256);                   // N
    int*    off    = (int*)(dinv + N_NODES);                  // N+2 (padded)
    int*    cursor = off + (N_NODES + 2);                     // N*REP, [i*REP+r]
    u64*    edge_s = (u64*)(cursor + (size_t)REP * N_NODES);  // E u64 (4.8 MB)
    ushort* wfh    = (ushort*)(edge_s + N_EDGES);             // 16384
    ushort* wfl    = wfh + 16384;                             // 16384
    size_t need = ((size_t)(wfl + 16384) - (size_t)d_ws);

    if (ws_size >= need) {
        int n2 = (int)(((size_t)REP * N_NODES * 8 + 256 * 8) / 16);
        prep_kernel<<<ZERO_BLOCKS + 8, 256, 0, stream>>>((ulonglong2*)degp, n2,
                                                         W, wfh, wfl);

        deg_cnt_kernel<<<FILL_BLOCKS, 256, 0, stream>>>(dst, ew, degp);

        scan_fused_kernel<<<NB, SCAN_B, 0, stream>>>(degp, dinv, off, cursor, flags);

        fused_fg_kernel<<<GEMM_BLOCKS + FILL_BLOCKS, 256, 0, stream>>>(
            x, wfh, wfl, hbf, src, dst, ew, dinv, cursor, edge_s);

        gather_kernel<<<(N_NODES + 3) / 4, 256, 0, stream>>>(off, edge_s, dinv,
                                                             hbf, b, out);
    } else {
        // ---- fallback: atomic scatter, f32 ----
        float* h    = (float*)d_ws;                 // N*D
        float* deg  = h + (size_t)N_NODES * D;      // N
        float* dv   = deg + N_NODES;                // N
        hipMemsetAsync(d_out, 0, (size_t)out_size * sizeof(float), stream);
        fb_init_kernel<<<(N_NODES + 255) / 256, 256, 0, stream>>>(deg);
        fb_deg_kernel<<<(N_EDGES + 255) / 256, 256, 0, stream>>>(dst, ew, deg);
        fb_dinv_kernel<<<(N_NODES + 255) / 256, 256, 0, stream>>>(deg, dv);
        fb_gemm_kernel<<<(N_NODES + 1) / 2, 256, 0, stream>>>(x, W, h);
        fb_scatter_kernel<<<(N_EDGES + 3) / 4, 256, 0, stream>>>(src, dst, ew, dv, h, out);
        fb_finalize_kernel<<<(N_NODES * D + 255) / 256, 256, 0, stream>>>(h, dv, b, out);
    }
}